// Round 16
// baseline (365.240 us; speedup 1.0000x reference)
//
#include <hip/hip_runtime.h>
#include <math.h>

#define NN 100000
#define NE 1600000
#define BN_EPS 1e-5f
#define NB 782            // buckets of 128 nodes
#define BCAP 4096         // fixed bucket capacity (avg 2046, sigma 45)
#define EPB 4096
#define NEB ((NE + EPB - 1) / EPB)   // 391
#define CVB 12500         // cvtx blocks

typedef short bf16x8 __attribute__((ext_vector_type(8)));
typedef float f32x4 __attribute__((ext_vector_type(4)));
typedef float f32x2 __attribute__((ext_vector_type(2)));
typedef unsigned short ushort;
typedef ushort us8 __attribute__((ext_vector_type(8)));
typedef ushort us4 __attribute__((ext_vector_type(4)));
typedef unsigned ui2 __attribute__((ext_vector_type(2)));

__device__ __forceinline__ ushort f2bf(float f) {
    unsigned u = __float_as_uint(f);
    unsigned r = (u + 0x7FFFu + ((u >> 16) & 1u)) >> 16;
    return (ushort)r;
}
__device__ __forceinline__ float bf2f(ushort h) { return __uint_as_float(((unsigned)h) << 16); }

// 8 fp8(e4m3) bytes -> 8 floats via HW cvt (gfx950 OCP format)
__device__ __forceinline__ void fp8x8_f32(ui2 q, float* f) {
    f32x2 p;
    p = __builtin_amdgcn_cvt_pk_f32_fp8((int)q[0], false); f[0] = p[0]; f[1] = p[1];
    p = __builtin_amdgcn_cvt_pk_f32_fp8((int)q[0], true);  f[2] = p[0]; f[3] = p[1];
    p = __builtin_amdgcn_cvt_pk_f32_fp8((int)q[1], false); f[4] = p[0]; f[5] = p[1];
    p = __builtin_amdgcn_cvt_pk_f32_fp8((int)q[1], true);  f[6] = p[0]; f[7] = p[1];
}
// 8 floats -> 8 fp8 bytes
__device__ __forceinline__ ui2 f32_fp8x8(const float* f) {
    int d0 = __builtin_amdgcn_cvt_pk_fp8_f32(f[0], f[1], 0, false);
    d0 = __builtin_amdgcn_cvt_pk_fp8_f32(f[2], f[3], d0, true);
    int d1 = __builtin_amdgcn_cvt_pk_fp8_f32(f[4], f[5], 0, false);
    d1 = __builtin_amdgcn_cvt_pk_fp8_f32(f[6], f[7], d1, true);
    ui2 r; r[0] = (unsigned)d0; r[1] = (unsigned)d1; return r;
}

// ---------------- prep1: edge scatter [0,NEB) || x convert [NEB,NEB+CVB) || W pack (rest) ----------------
__global__ __launch_bounds__(256) void prep1_k(const int* __restrict__ ei, int* __restrict__ bcur,
                                               unsigned* __restrict__ packed,
                                               const float* __restrict__ x, ushort* __restrict__ xb,
                                               unsigned* __restrict__ xq,
                                               const float* __restrict__ Wa, const float* __restrict__ Wb,
                                               const float* __restrict__ Wc, const float* __restrict__ Wd,
                                               const float* __restrict__ We, const float* __restrict__ Wf_,
                                               ushort* __restrict__ Fa, ushort* __restrict__ Fb,
                                               ushort* __restrict__ Fc, ushort* __restrict__ Fd,
                                               ushort* __restrict__ Fe, ushort* __restrict__ Ff) {
    __shared__ int h[NB];
    if (blockIdx.x >= NEB + CVB) {
        // ---- packall part ----
        int bb = blockIdx.x - (NEB + CVB);
        int which = bb >> 3, sub = bb & 7;
        const float* W; ushort* F; int DOUT = 128;
        switch (which) {
            case 0: W = Wa; F = Fa; break;
            case 1: W = Wb; F = Fb; break;
            case 2: W = Wc; F = Fc; break;
            case 3: W = Wd; F = Fd; break;
            case 4: W = We; F = Fe; break;
            default: W = Wf_; F = Ff; DOUT = 64; break;
        }
        int NT = DOUT / 16;
        int idx = sub * 256 + threadIdx.x;
        if (idx >= 4 * NT * 64) return;
        int l = idx & 63;
        int nt = (idx >> 6) % NT;
        int kt = idx / (NT * 64);
        int colw = nt * 16 + (l & 15);
        int k0 = kt * 32 + (l >> 4) * 8;
        us8 o;
#pragma unroll
        for (int e = 0; e < 8; ++e) o[e] = f2bf(W[(k0 + e) * DOUT + colw]);
        ((us8*)F)[idx] = o;
        return;
    }
    if (blockIdx.x >= NEB) {
        // ---- cvtx part: fp32 -> bf16 + fp8 ----
        int i = (blockIdx.x - NEB) * 256 + threadIdx.x;
        float4 v = ((const float4*)x)[i];
        us4 o;
        o[0] = f2bf(v.x); o[1] = f2bf(v.y); o[2] = f2bf(v.z); o[3] = f2bf(v.w);
        ((us4*)xb)[i] = o;
        int d = __builtin_amdgcn_cvt_pk_fp8_f32(v.x, v.y, 0, false);
        d = __builtin_amdgcn_cvt_pk_fp8_f32(v.z, v.w, d, true);
        xq[i] = (unsigned)d;
        return;
    }
    // ---- bscat part (bcur zeroed beforehand) ----
    for (int i = threadIdx.x; i < NB; i += 256) h[i] = 0;
    __syncthreads();
    int base = blockIdx.x * EPB;
    for (int i = threadIdx.x; i < EPB; i += 256) {
        int e = base + i;
        if (e < NE) atomicAdd(&h[ei[NE + e] >> 7], 1);
    }
    __syncthreads();
    for (int i = threadIdx.x; i < NB; i += 256) {
        int c = h[i];
        if (c) h[i] = (i << 12) + atomicAdd(&bcur[i], c);
    }
    __syncthreads();
    for (int i = threadIdx.x; i < EPB; i += 256) {
        int e = base + i;
        if (e < NE) {
            int d = ei[NE + e];
            int b = d >> 7;
            int pos = atomicAdd(&h[b], 1);
            packed[pos] = (unsigned)ei[e] | ((unsigned)(d & 127) << 17);
        }
    }
}

// ---------------- prep2: per-bucket CSR counting sort + degree perm ----------------
__global__ __launch_bounds__(256) void prep2_k(unsigned* __restrict__ packed, const int* __restrict__ bcur,
                                               int* __restrict__ rpS, int* __restrict__ rpE,
                                               int* __restrict__ perm) {
    __shared__ unsigned ent[BCAP];     // 16 KB
    __shared__ int hc[128], hb[128], sc[128];
    int t = threadIdx.x, b = blockIdx.x;
    int base = b << 12;
    int nb = bcur[b];                  // per-bucket count (0-based cursors)
    if (nb > BCAP) nb = BCAP;
    for (int i = t; i < nb; i += 256) ent[i] = packed[base + i];
    if (t < 128) hc[t] = 0;
    __syncthreads();
    for (int i = t; i < nb; i += 256) atomicAdd(&hc[ent[i] >> 17], 1);
    __syncthreads();
    if (t < 128) sc[t] = hc[t];
    __syncthreads();
    for (int off = 1; off < 128; off <<= 1) {
        int u = 0;
        if (t < 128 && t >= off) u = sc[t - off];
        __syncthreads();
        if (t < 128) sc[t] += u;
        __syncthreads();
    }
    if (t < 128) {
        int ex = sc[t] - hc[t];
        hb[t] = ex;
        int node = b * 128 + t;
        if (node < NN) {
            rpS[node] = base + ex;
            rpE[node] = base + sc[t];
        }
    }
    __syncthreads();
    for (int i = t; i < nb; i += 256) {
        unsigned u = ent[i];
        int pos = atomicAdd(&hb[u >> 17], 1);
        packed[base + pos] = u & 0x1FFFFu;
    }
    // degree-rank each 64-node tile -> perm
    if (t < 128) {
        int half = t >> 6, li = t & 63;
        int mydeg = (b * 128 + t < NN) ? hc[t] : -1;
        int rank = 0;
#pragma unroll 8
        for (int j = 0; j < 64; ++j) {
            int oj = half * 64 + j;
            int od = (b * 128 + oj < NN) ? hc[oj] : -1;
            rank += (od > mydeg) || (od == mydeg && j < li);
        }
        perm[(b * 2 + half) * 64 + rank] = li;
    }
}

// ---------------- fused layer: fp8 gather-agg (degree-sorted) -> Alds -> MLP (2 row-halves) -> epilogue ----
// 256 threads = 4 waves, 64 rows/block. LDS 24.8KB -> 6 blocks/CU (occupancy push).
// MLP runs in two 32-row halves sharing an 8KB Hlds.
// FINAL=0: BN+relu+residual -> bf16 outb + fp8 outq.  FINAL=1: log_softmax -> fp32 outf.
template <int FINAL>
__global__ __launch_bounds__(256, 6) void fused_k(
    const ushort* __restrict__ X, const unsigned* __restrict__ XQ,
    const int* __restrict__ rpS, const int* __restrict__ rpE,
    const unsigned* __restrict__ col, const int* __restrict__ perm,
    const ushort* __restrict__ W1f, const ushort* __restrict__ W2f,
    const float* __restrict__ b1, const float* __restrict__ b2,
    const float* __restrict__ bng, const float* __restrict__ bnb,
    const float* __restrict__ bnm, const float* __restrict__ bnv,
    ushort* __restrict__ outb, unsigned* __restrict__ outq, float* __restrict__ outf) {
    __shared__ ushort Alds[8192];   // 16KB: 64 x 128 bf16, XOR-swizzled
    __shared__ ushort Hlds[4096];   // 8KB: 32 x 128 bf16, XOR-swizzled (per half)
    __shared__ int pLds[64];
    const int t = threadIdx.x;
    const int w = t >> 6, l = t & 63;
    const int lrow = l & 15, lchk = l >> 4;
    const int R0 = blockIdx.x * 64;
    const us8* __restrict__ xv = (const us8*)X;
    const ui2* __restrict__ xq2 = (const ui2*)XQ;

    if (t < 64) pLds[t] = perm[blockIdx.x * 64 + t];
    __syncthreads();

    // ---- gather-aggregate: 4 iterations x 16 nodes, 16 lanes (8 features) per node ----
    const int ch = t & 15;
#pragma unroll
    for (int it = 0; it < 4; ++it) {
        int nl = pLds[it * 16 + (t >> 4)];
        int node = R0 + nl;
        float a[8];
#pragma unroll
        for (int i = 0; i < 8; ++i) a[i] = 0.f;
        if (node < NN) {
            us8 self = xv[(size_t)node * 16 + ch];
#pragma unroll
            for (int i = 0; i < 8; ++i) a[i] = bf2f(self[i]);
            int p = rpS[node];
            const int pe = rpE[node];
            for (; p + 7 < pe; p += 8) {
                unsigned s[8];
#pragma unroll
                for (int u = 0; u < 8; ++u) s[u] = col[p + u];
                ui2 v[8];
#pragma unroll
                for (int u = 0; u < 8; ++u) v[u] = xq2[(size_t)s[u] * 16 + ch];
#pragma unroll
                for (int u = 0; u < 8; ++u) {
                    float f[8];
                    fp8x8_f32(v[u], f);
#pragma unroll
                    for (int i = 0; i < 8; ++i) a[i] += f[i];
                }
            }
            for (; p + 3 < pe; p += 4) {
                ui2 v0 = xq2[(size_t)col[p] * 16 + ch];
                ui2 v1 = xq2[(size_t)col[p + 1] * 16 + ch];
                ui2 v2 = xq2[(size_t)col[p + 2] * 16 + ch];
                ui2 v3 = xq2[(size_t)col[p + 3] * 16 + ch];
                float f0[8], f1[8], f2[8], f3[8];
                fp8x8_f32(v0, f0); fp8x8_f32(v1, f1); fp8x8_f32(v2, f2); fp8x8_f32(v3, f3);
#pragma unroll
                for (int i = 0; i < 8; ++i) a[i] += (f0[i] + f1[i]) + (f2[i] + f3[i]);
            }
            for (; p < pe; ++p) {
                ui2 v = xq2[(size_t)col[p] * 16 + ch];
                float f[8];
                fp8x8_f32(v, f);
#pragma unroll
                for (int i = 0; i < 8; ++i) a[i] += f[i];
            }
        }
        us8 o;
#pragma unroll
        for (int i = 0; i < 8; ++i) o[i] = f2bf(a[i]);
        int byte = (nl * 256 + ch * 16) ^ ((nl & 7) << 4);
        *(us8*)((char*)Alds + byte) = o;
    }

    // W1/W2 frags + BN consts (registers, reused across halves)
    const bf16x8* __restrict__ w1p = (const bf16x8*)W1f;
    bf16x8 w1r[2][4];
#pragma unroll
    for (int ntl = 0; ntl < 2; ++ntl)
#pragma unroll
        for (int kt = 0; kt < 4; ++kt)
            w1r[ntl][kt] = w1p[(kt * 8 + (2 * w + ntl)) * 64 + l];
    bf16x8 w2r[2][4];
    float sc[2], of[2];
    if constexpr (FINAL == 0) {
        const bf16x8* __restrict__ w2p = (const bf16x8*)W2f;
#pragma unroll
        for (int ntl = 0; ntl < 2; ++ntl)
#pragma unroll
            for (int kt = 0; kt < 4; ++kt)
                w2r[ntl][kt] = w2p[(kt * 8 + (2 * w + ntl)) * 64 + l];
#pragma unroll
        for (int ntl = 0; ntl < 2; ++ntl) {
            int colb = (2 * w + ntl) * 16 + lrow;
            sc[ntl] = bng[colb] * rsqrtf(bnv[colb] + BN_EPS);
            of[ntl] = (b2[colb] - bnm[colb]) * sc[ntl] + bnb[colb];
        }
    }

    __syncthreads();

    // ---- MLP in two 32-row halves (8KB Hlds) ----
#pragma unroll
    for (int hh = 0; hh < 2; ++hh) {
        // stage 1: h = relu(agg @ W1 + b1) for rows [hh*32, hh*32+32)
#pragma unroll
        for (int mt = 0; mt < 2; ++mt) {
            bf16x8 af[4];
#pragma unroll
            for (int kt = 0; kt < 4; ++kt) {
                int row = hh * 32 + mt * 16 + lrow;
                int byte = (row * 256 + kt * 64 + lchk * 16) ^ ((row & 7) << 4);
                af[kt] = *(const bf16x8*)((char*)Alds + byte);
            }
            f32x4 acc[2] = {f32x4{0.f, 0.f, 0.f, 0.f}, f32x4{0.f, 0.f, 0.f, 0.f}};
#pragma unroll
            for (int kt = 0; kt < 4; ++kt)
#pragma unroll
                for (int ntl = 0; ntl < 2; ++ntl)
                    acc[ntl] = __builtin_amdgcn_mfma_f32_16x16x32_bf16(af[kt], w1r[ntl][kt], acc[ntl], 0, 0, 0);
#pragma unroll
            for (int ntl = 0; ntl < 2; ++ntl) {
                int colb = (2 * w + ntl) * 16 + lrow;
                float bias = b1[colb];
#pragma unroll
                for (int r = 0; r < 4; ++r) {
                    int rloc = mt * 16 + lchk * 4 + r;   // local row in half
                    float hv = fmaxf(acc[ntl][r] + bias, 0.f);
                    int byte = (rloc * 256 + colb * 2) ^ ((rloc & 7) << 4);
                    *(ushort*)((char*)Hlds + byte) = f2bf(hv);
                }
            }
        }
        __syncthreads();
        // stage 2
        if constexpr (FINAL == 0) {
#pragma unroll
            for (int mt = 0; mt < 2; ++mt) {
                bf16x8 hf[4];
#pragma unroll
                for (int kt = 0; kt < 4; ++kt) {
                    int rloc = mt * 16 + lrow;
                    int byte = (rloc * 256 + kt * 64 + lchk * 16) ^ ((rloc & 7) << 4);
                    hf[kt] = *(const bf16x8*)((char*)Hlds + byte);
                }
                f32x4 acc2[2] = {f32x4{0.f, 0.f, 0.f, 0.f}, f32x4{0.f, 0.f, 0.f, 0.f}};
#pragma unroll
                for (int kt = 0; kt < 4; ++kt)
#pragma unroll
                    for (int ntl = 0; ntl < 2; ++ntl)
                        acc2[ntl] = __builtin_amdgcn_mfma_f32_16x16x32_bf16(hf[kt], w2r[ntl][kt], acc2[ntl], 0, 0, 0);
                // BN+relu -> bf16 into Alds rows of this half (agg already consumed)
#pragma unroll
                for (int ntl = 0; ntl < 2; ++ntl) {
                    int colb = (2 * w + ntl) * 16 + lrow;
#pragma unroll
                    for (int r = 0; r < 4; ++r) {
                        int row = hh * 32 + mt * 16 + lchk * 4 + r;
                        float o = fmaxf(acc2[ntl][r] * sc[ntl] + of[ntl], 0.f);
                        int byte = (row * 256 + colb * 2) ^ ((row & 7) << 4);
                        *(ushort*)((char*)Alds + byte) = f2bf(o);
                    }
                }
            }
        } else {
            // DOUT=64: waves 0,1 handle the half's two 16-row tiles (row-local softmax)
            if (w < 2) {
                const bf16x8* __restrict__ w2p = (const bf16x8*)W2f;
                bf16x8 hf[4];
#pragma unroll
                for (int kt = 0; kt < 4; ++kt) {
                    int rloc = w * 16 + lrow;
                    int byte = (rloc * 256 + kt * 64 + lchk * 16) ^ ((rloc & 7) << 4);
                    hf[kt] = *(const bf16x8*)((char*)Hlds + byte);
                }
                f32x4 acc2[4];
#pragma unroll
                for (int nt = 0; nt < 4; ++nt) acc2[nt] = f32x4{0.f, 0.f, 0.f, 0.f};
#pragma unroll
                for (int kt = 0; kt < 4; ++kt)
#pragma unroll
                    for (int nt = 0; nt < 4; ++nt)
                        acc2[nt] = __builtin_amdgcn_mfma_f32_16x16x32_bf16(hf[kt], w2p[(kt * 4 + nt) * 64 + l], acc2[nt], 0, 0, 0);
                float bb[4];
#pragma unroll
                for (int nt = 0; nt < 4; ++nt) bb[nt] = b2[nt * 16 + lrow];
#pragma unroll
                for (int r = 0; r < 4; ++r) {
                    float v0 = acc2[0][r] + bb[0], v1 = acc2[1][r] + bb[1];
                    float v2 = acc2[2][r] + bb[2], v3 = acc2[3][r] + bb[3];
                    float mx = fmaxf(fmaxf(v0, v1), fmaxf(v2, v3));
                    for (int d = 1; d < 16; d <<= 1) mx = fmaxf(mx, __shfl_xor(mx, d));
                    float sm = expf(v0 - mx) + expf(v1 - mx) + expf(v2 - mx) + expf(v3 - mx);
                    for (int d = 1; d < 16; d <<= 1) sm += __shfl_xor(sm, d);
                    float L = mx + logf(sm);
                    int grow = R0 + hh * 32 + w * 16 + lchk * 4 + r;
                    if (grow < NN) {
                        outf[(size_t)grow * 64 + 0 + lrow] = v0 - L;
                        outf[(size_t)grow * 64 + 16 + lrow] = v1 - L;
                        outf[(size_t)grow * 64 + 32 + lrow] = v2 - L;
                        outf[(size_t)grow * 64 + 48 + lrow] = v3 - L;
                    }
                }
            }
        }
        __syncthreads();
    }

    // ---- epilogue repack: coalesced residual add + dual store (bf16 + fp8) ----
    if constexpr (FINAL == 0) {
        us8* __restrict__ ob8 = (us8*)outb;
        ui2* __restrict__ oq2 = (ui2*)outq;
#pragma unroll
        for (int j = 0; j < 4; ++j) {
            int i = t + 256 * j;
            int row = i >> 4, chunk = i & 15;
            int grow = R0 + row;
            if (grow < NN) {
                int byte = (row * 256 + chunk * 16) ^ ((row & 7) << 4);
                us8 h8 = *(const us8*)((char*)Alds + byte);
                us8 r8 = xv[(size_t)grow * 16 + chunk];
                float oo[8];
#pragma unroll
                for (int e = 0; e < 8; ++e) oo[e] = bf2f(h8[e]) + bf2f(r8[e]);
                us8 o8;
#pragma unroll
                for (int e = 0; e < 8; ++e) o8[e] = f2bf(oo[e]);
                ob8[(size_t)grow * 16 + chunk] = o8;
                oq2[(size_t)grow * 16 + chunk] = f32_fp8x8(oo);
            }
        }
    }
}

extern "C" void kernel_launch(void* const* d_in, const int* in_sizes, int n_in,
                              void* d_out, int out_size, void* d_ws, size_t ws_size,
                              hipStream_t stream) {
    const float* x = (const float*)d_in[0];
    const int* ei = (const int*)d_in[1];
    const float* W1_0 = (const float*)d_in[2];
    const float* b1_0 = (const float*)d_in[3];
    const float* W2_0 = (const float*)d_in[4];
    const float* b2_0 = (const float*)d_in[5];
    const float* W1_1 = (const float*)d_in[6];
    const float* b1_1 = (const float*)d_in[7];
    const float* W2_1 = (const float*)d_in[8];
    const float* b2_1 = (const float*)d_in[9];
    const float* W1_2 = (const float*)d_in[10];
    const float* b1_2 = (const float*)d_in[11];
    const float* W2_2 = (const float*)d_in[12];
    const float* b2_2 = (const float*)d_in[13];
    const float* g0 = (const float*)d_in[14];
    const float* be0 = (const float*)d_in[15];
    const float* m0 = (const float*)d_in[16];
    const float* v0 = (const float*)d_in[17];
    const float* g1 = (const float*)d_in[18];
    const float* be1 = (const float*)d_in[19];
    const float* m1 = (const float*)d_in[20];
    const float* v1 = (const float*)d_in[21];
    float* out = (float*)d_out;

    // ws layout (bytes): xb0 25.6M | xb1 25.6M | xq0 12.8M | xq1 12.8M |
    // packed/col 12.8M | rpS 400K | rpE 400K | bcur 4K | perm 401K | Wf
    char* ws = (char*)d_ws;
    ushort* xb0 = (ushort*)(ws);
    ushort* xb1 = (ushort*)(ws + 25600000);
    unsigned* xq0 = (unsigned*)(ws + 51200000);
    unsigned* xq1 = (unsigned*)(ws + 64000000);
    unsigned* packed = (unsigned*)(ws + 76800000);     // also final col
    int* rpS = (int*)(ws + 76800000 + 12812288);
    int* rpE = (int*)(ws + 76800000 + 12812288 + 400128);
    int* bcur = (int*)(ws + 76800000 + 12812288 + 800256);
    int* perm = (int*)(ws + 76800000 + 12812288 + 800256 + 4096);   // NB*2*64 ints
    ushort* W10f = (ushort*)(ws + 76800000 + 12812288 + 800256 + 4096 + 401408);
    ushort* W20f = W10f + 16384;
    ushort* W11f = W20f + 16384;
    ushort* W21f = W11f + 16384;
    ushort* W12f = W21f + 16384;
    ushort* W22f = W12f + 16384;

    // --- prep (overlapped): zero cursors; scatter || convert || pack; then CSR sort ---
    hipMemsetAsync(bcur, 0, NB * sizeof(int), stream);
    prep1_k<<<NEB + CVB + 48, 256, 0, stream>>>(ei, bcur, packed, x, xb0, xq0,
                                                W1_0, W2_0, W1_1, W2_1, W1_2, W2_2,
                                                W10f, W20f, W11f, W21f, W12f, W22f);
    prep2_k<<<NB, 256, 0, stream>>>(packed, bcur, rpS, rpE, perm);

    const int GG = (NN + 63) / 64;  // 1563

    // one fused kernel per layer: fp8 gather-agg + MLP + epilogue
    fused_k<0><<<GG, 256, 0, stream>>>(xb0, xq0, rpS, rpE, packed, perm, W10f, W20f, b1_0, b2_0,
                                       g0, be0, m0, v0, xb1, xq1, nullptr);
    fused_k<0><<<GG, 256, 0, stream>>>(xb1, xq1, rpS, rpE, packed, perm, W11f, W21f, b1_1, b2_1,
                                       g1, be1, m1, v1, xb0, xq0, nullptr);
    fused_k<1><<<GG, 256, 0, stream>>>(xb0, xq0, rpS, rpE, packed, perm, W12f, W22f, b1_2, b2_2,
                                       nullptr, nullptr, nullptr, nullptr, nullptr, nullptr, out);
}

// Round 17
// 247.754 us; speedup vs baseline: 1.4742x; 1.4742x over previous
//
#include <hip/hip_runtime.h>
#include <math.h>

#define NN 100000
#define NE 1600000
#define BN_EPS 1e-5f
#define NB 782            // buckets of 128 nodes
#define BCAP 4096         // fixed bucket capacity (avg 2046, sigma 45)
#define EPB 4096
#define NEB ((NE + EPB - 1) / EPB)   // 391
#define CVB 12500         // cvtx blocks

typedef short bf16x8 __attribute__((ext_vector_type(8)));
typedef float f32x4 __attribute__((ext_vector_type(4)));
typedef float f32x2 __attribute__((ext_vector_type(2)));
typedef unsigned short ushort;
typedef ushort us8 __attribute__((ext_vector_type(8)));
typedef ushort us4 __attribute__((ext_vector_type(4)));
typedef unsigned ui2 __attribute__((ext_vector_type(2)));

__device__ __forceinline__ ushort f2bf(float f) {
    unsigned u = __float_as_uint(f);
    unsigned r = (u + 0x7FFFu + ((u >> 16) & 1u)) >> 16;
    return (ushort)r;
}
__device__ __forceinline__ float bf2f(ushort h) { return __uint_as_float(((unsigned)h) << 16); }

// 8 fp8(e4m3) bytes -> 8 floats via HW cvt (gfx950 OCP format)
__device__ __forceinline__ void fp8x8_f32(ui2 q, float* f) {
    f32x2 p;
    p = __builtin_amdgcn_cvt_pk_f32_fp8((int)q[0], false); f[0] = p[0]; f[1] = p[1];
    p = __builtin_amdgcn_cvt_pk_f32_fp8((int)q[0], true);  f[2] = p[0]; f[3] = p[1];
    p = __builtin_amdgcn_cvt_pk_f32_fp8((int)q[1], false); f[4] = p[0]; f[5] = p[1];
    p = __builtin_amdgcn_cvt_pk_f32_fp8((int)q[1], true);  f[6] = p[0]; f[7] = p[1];
}
// 8 floats -> 8 fp8 bytes
__device__ __forceinline__ ui2 f32_fp8x8(const float* f) {
    int d0 = __builtin_amdgcn_cvt_pk_fp8_f32(f[0], f[1], 0, false);
    d0 = __builtin_amdgcn_cvt_pk_fp8_f32(f[2], f[3], d0, true);
    int d1 = __builtin_amdgcn_cvt_pk_fp8_f32(f[4], f[5], 0, false);
    d1 = __builtin_amdgcn_cvt_pk_fp8_f32(f[6], f[7], d1, true);
    ui2 r; r[0] = (unsigned)d0; r[1] = (unsigned)d1; return r;
}

// ---------------- prep1: edge scatter [0,NEB) || x convert [NEB,NEB+CVB) || W pack (rest) ----------------
__global__ __launch_bounds__(256) void prep1_k(const int* __restrict__ ei, int* __restrict__ bcur,
                                               unsigned* __restrict__ packed,
                                               const float* __restrict__ x, ushort* __restrict__ xb,
                                               unsigned* __restrict__ xq,
                                               const float* __restrict__ Wa, const float* __restrict__ Wb,
                                               const float* __restrict__ Wc, const float* __restrict__ Wd,
                                               const float* __restrict__ We, const float* __restrict__ Wf_,
                                               ushort* __restrict__ Fa, ushort* __restrict__ Fb,
                                               ushort* __restrict__ Fc, ushort* __restrict__ Fd,
                                               ushort* __restrict__ Fe, ushort* __restrict__ Ff) {
    __shared__ int h[NB];
    if (blockIdx.x >= NEB + CVB) {
        // ---- packall part ----
        int bb = blockIdx.x - (NEB + CVB);
        int which = bb >> 3, sub = bb & 7;
        const float* W; ushort* F; int DOUT = 128;
        switch (which) {
            case 0: W = Wa; F = Fa; break;
            case 1: W = Wb; F = Fb; break;
            case 2: W = Wc; F = Fc; break;
            case 3: W = Wd; F = Fd; break;
            case 4: W = We; F = Fe; break;
            default: W = Wf_; F = Ff; DOUT = 64; break;
        }
        int NT = DOUT / 16;
        int idx = sub * 256 + threadIdx.x;
        if (idx >= 4 * NT * 64) return;
        int l = idx & 63;
        int nt = (idx >> 6) % NT;
        int kt = idx / (NT * 64);
        int colw = nt * 16 + (l & 15);
        int k0 = kt * 32 + (l >> 4) * 8;
        us8 o;
#pragma unroll
        for (int e = 0; e < 8; ++e) o[e] = f2bf(W[(k0 + e) * DOUT + colw]);
        ((us8*)F)[idx] = o;
        return;
    }
    if (blockIdx.x >= NEB) {
        // ---- cvtx part: fp32 -> bf16 + fp8 ----
        int i = (blockIdx.x - NEB) * 256 + threadIdx.x;
        float4 v = ((const float4*)x)[i];
        us4 o;
        o[0] = f2bf(v.x); o[1] = f2bf(v.y); o[2] = f2bf(v.z); o[3] = f2bf(v.w);
        ((us4*)xb)[i] = o;
        int d = __builtin_amdgcn_cvt_pk_fp8_f32(v.x, v.y, 0, false);
        d = __builtin_amdgcn_cvt_pk_fp8_f32(v.z, v.w, d, true);
        xq[i] = (unsigned)d;
        return;
    }
    // ---- bscat part (bcur zeroed beforehand) ----
    for (int i = threadIdx.x; i < NB; i += 256) h[i] = 0;
    __syncthreads();
    int base = blockIdx.x * EPB;
    for (int i = threadIdx.x; i < EPB; i += 256) {
        int e = base + i;
        if (e < NE) atomicAdd(&h[ei[NE + e] >> 7], 1);
    }
    __syncthreads();
    for (int i = threadIdx.x; i < NB; i += 256) {
        int c = h[i];
        if (c) h[i] = (i << 12) + atomicAdd(&bcur[i], c);
    }
    __syncthreads();
    for (int i = threadIdx.x; i < EPB; i += 256) {
        int e = base + i;
        if (e < NE) {
            int d = ei[NE + e];
            int b = d >> 7;
            int pos = atomicAdd(&h[b], 1);
            packed[pos] = (unsigned)ei[e] | ((unsigned)(d & 127) << 17);
        }
    }
}

// ---------------- prep2: per-bucket CSR counting sort + degree perm ----------------
__global__ __launch_bounds__(256) void prep2_k(unsigned* __restrict__ packed, const int* __restrict__ bcur,
                                               int* __restrict__ rpS, int* __restrict__ rpE,
                                               int* __restrict__ perm) {
    __shared__ unsigned ent[BCAP];     // 16 KB
    __shared__ int hc[128], hb[128], sc[128];
    int t = threadIdx.x, b = blockIdx.x;
    int base = b << 12;
    int nb = bcur[b];                  // per-bucket count (0-based cursors)
    if (nb > BCAP) nb = BCAP;
    for (int i = t; i < nb; i += 256) ent[i] = packed[base + i];
    if (t < 128) hc[t] = 0;
    __syncthreads();
    for (int i = t; i < nb; i += 256) atomicAdd(&hc[ent[i] >> 17], 1);
    __syncthreads();
    if (t < 128) sc[t] = hc[t];
    __syncthreads();
    for (int off = 1; off < 128; off <<= 1) {
        int u = 0;
        if (t < 128 && t >= off) u = sc[t - off];
        __syncthreads();
        if (t < 128) sc[t] += u;
        __syncthreads();
    }
    if (t < 128) {
        int ex = sc[t] - hc[t];
        hb[t] = ex;
        int node = b * 128 + t;
        if (node < NN) {
            rpS[node] = base + ex;
            rpE[node] = base + sc[t];
        }
    }
    __syncthreads();
    for (int i = t; i < nb; i += 256) {
        unsigned u = ent[i];
        int pos = atomicAdd(&hb[u >> 17], 1);
        packed[base + pos] = u & 0x1FFFFu;
    }
    // degree-rank each 64-node tile -> perm
    if (t < 128) {
        int half = t >> 6, li = t & 63;
        int mydeg = (b * 128 + t < NN) ? hc[t] : -1;
        int rank = 0;
#pragma unroll 8
        for (int j = 0; j < 64; ++j) {
            int oj = half * 64 + j;
            int od = (b * 128 + oj < NN) ? hc[oj] : -1;
            rank += (od > mydeg) || (od == mydeg && j < li);
        }
        perm[(b * 2 + half) * 64 + rank] = li;
    }
}

// ---------------- fused layer: fp8 gather-agg (degree-sorted) -> Alds -> MLP (2 row-halves) -> epilogue ----
// 256 threads = 4 waves, 64 rows/block. LDS 24.8KB -> 6 blocks/CU by LDS; launch_bounds
// (256,4) keeps VGPR cap at 128 so the gather's register working set never spills
// (R16's (256,6) forced VGPR=40 -> scratch spill catastrophe).
// FINAL=0: BN+relu+residual -> bf16 outb + fp8 outq.  FINAL=1: log_softmax -> fp32 outf.
template <int FINAL>
__global__ __launch_bounds__(256, 4) void fused_k(
    const ushort* __restrict__ X, const unsigned* __restrict__ XQ,
    const int* __restrict__ rpS, const int* __restrict__ rpE,
    const unsigned* __restrict__ col, const int* __restrict__ perm,
    const ushort* __restrict__ W1f, const ushort* __restrict__ W2f,
    const float* __restrict__ b1, const float* __restrict__ b2,
    const float* __restrict__ bng, const float* __restrict__ bnb,
    const float* __restrict__ bnm, const float* __restrict__ bnv,
    ushort* __restrict__ outb, unsigned* __restrict__ outq, float* __restrict__ outf) {
    __shared__ ushort Alds[8192];   // 16KB: 64 x 128 bf16, XOR-swizzled
    __shared__ ushort Hlds[4096];   // 8KB: 32 x 128 bf16, XOR-swizzled (per half)
    __shared__ int pLds[64];
    const int t = threadIdx.x;
    const int w = t >> 6, l = t & 63;
    const int lrow = l & 15, lchk = l >> 4;
    const int R0 = blockIdx.x * 64;
    const us8* __restrict__ xv = (const us8*)X;
    const ui2* __restrict__ xq2 = (const ui2*)XQ;

    if (t < 64) pLds[t] = perm[blockIdx.x * 64 + t];
    __syncthreads();

    // ---- gather-aggregate: 4 iterations x 16 nodes, 16 lanes (8 features) per node ----
    const int ch = t & 15;
#pragma unroll
    for (int it = 0; it < 4; ++it) {
        int nl = pLds[it * 16 + (t >> 4)];
        int node = R0 + nl;
        float a[8];
#pragma unroll
        for (int i = 0; i < 8; ++i) a[i] = 0.f;
        if (node < NN) {
            us8 self = xv[(size_t)node * 16 + ch];
#pragma unroll
            for (int i = 0; i < 8; ++i) a[i] = bf2f(self[i]);
            int p = rpS[node];
            const int pe = rpE[node];
            for (; p + 7 < pe; p += 8) {
                unsigned s[8];
#pragma unroll
                for (int u = 0; u < 8; ++u) s[u] = col[p + u];
                ui2 v[8];
#pragma unroll
                for (int u = 0; u < 8; ++u) v[u] = xq2[(size_t)s[u] * 16 + ch];
#pragma unroll
                for (int u = 0; u < 8; ++u) {
                    float f[8];
                    fp8x8_f32(v[u], f);
#pragma unroll
                    for (int i = 0; i < 8; ++i) a[i] += f[i];
                }
            }
            for (; p + 3 < pe; p += 4) {
                ui2 v0 = xq2[(size_t)col[p] * 16 + ch];
                ui2 v1 = xq2[(size_t)col[p + 1] * 16 + ch];
                ui2 v2 = xq2[(size_t)col[p + 2] * 16 + ch];
                ui2 v3 = xq2[(size_t)col[p + 3] * 16 + ch];
                float f0[8], f1[8], f2[8], f3[8];
                fp8x8_f32(v0, f0); fp8x8_f32(v1, f1); fp8x8_f32(v2, f2); fp8x8_f32(v3, f3);
#pragma unroll
                for (int i = 0; i < 8; ++i) a[i] += (f0[i] + f1[i]) + (f2[i] + f3[i]);
            }
            for (; p < pe; ++p) {
                ui2 v = xq2[(size_t)col[p] * 16 + ch];
                float f[8];
                fp8x8_f32(v, f);
#pragma unroll
                for (int i = 0; i < 8; ++i) a[i] += f[i];
            }
        }
        us8 o;
#pragma unroll
        for (int i = 0; i < 8; ++i) o[i] = f2bf(a[i]);
        int byte = (nl * 256 + ch * 16) ^ ((nl & 7) << 4);
        *(us8*)((char*)Alds + byte) = o;
    }

    // W1/W2 frags + BN consts (registers, reused across halves)
    const bf16x8* __restrict__ w1p = (const bf16x8*)W1f;
    bf16x8 w1r[2][4];
#pragma unroll
    for (int ntl = 0; ntl < 2; ++ntl)
#pragma unroll
        for (int kt = 0; kt < 4; ++kt)
            w1r[ntl][kt] = w1p[(kt * 8 + (2 * w + ntl)) * 64 + l];
    bf16x8 w2r[2][4];
    float sc[2], of[2];
    if constexpr (FINAL == 0) {
        const bf16x8* __restrict__ w2p = (const bf16x8*)W2f;
#pragma unroll
        for (int ntl = 0; ntl < 2; ++ntl)
#pragma unroll
            for (int kt = 0; kt < 4; ++kt)
                w2r[ntl][kt] = w2p[(kt * 8 + (2 * w + ntl)) * 64 + l];
#pragma unroll
        for (int ntl = 0; ntl < 2; ++ntl) {
            int colb = (2 * w + ntl) * 16 + lrow;
            sc[ntl] = bng[colb] * rsqrtf(bnv[colb] + BN_EPS);
            of[ntl] = (b2[colb] - bnm[colb]) * sc[ntl] + bnb[colb];
        }
    }

    __syncthreads();

    // ---- MLP in two 32-row halves (8KB Hlds) ----
#pragma unroll
    for (int hh = 0; hh < 2; ++hh) {
        // stage 1: h = relu(agg @ W1 + b1) for rows [hh*32, hh*32+32)
#pragma unroll
        for (int mt = 0; mt < 2; ++mt) {
            bf16x8 af[4];
#pragma unroll
            for (int kt = 0; kt < 4; ++kt) {
                int row = hh * 32 + mt * 16 + lrow;
                int byte = (row * 256 + kt * 64 + lchk * 16) ^ ((row & 7) << 4);
                af[kt] = *(const bf16x8*)((char*)Alds + byte);
            }
            f32x4 acc[2] = {f32x4{0.f, 0.f, 0.f, 0.f}, f32x4{0.f, 0.f, 0.f, 0.f}};
#pragma unroll
            for (int kt = 0; kt < 4; ++kt)
#pragma unroll
                for (int ntl = 0; ntl < 2; ++ntl)
                    acc[ntl] = __builtin_amdgcn_mfma_f32_16x16x32_bf16(af[kt], w1r[ntl][kt], acc[ntl], 0, 0, 0);
#pragma unroll
            for (int ntl = 0; ntl < 2; ++ntl) {
                int colb = (2 * w + ntl) * 16 + lrow;
                float bias = b1[colb];
#pragma unroll
                for (int r = 0; r < 4; ++r) {
                    int rloc = mt * 16 + lchk * 4 + r;   // local row in half
                    float hv = fmaxf(acc[ntl][r] + bias, 0.f);
                    int byte = (rloc * 256 + colb * 2) ^ ((rloc & 7) << 4);
                    *(ushort*)((char*)Hlds + byte) = f2bf(hv);
                }
            }
        }
        __syncthreads();
        // stage 2
        if constexpr (FINAL == 0) {
#pragma unroll
            for (int mt = 0; mt < 2; ++mt) {
                bf16x8 hf[4];
#pragma unroll
                for (int kt = 0; kt < 4; ++kt) {
                    int rloc = mt * 16 + lrow;
                    int byte = (rloc * 256 + kt * 64 + lchk * 16) ^ ((rloc & 7) << 4);
                    hf[kt] = *(const bf16x8*)((char*)Hlds + byte);
                }
                f32x4 acc2[2] = {f32x4{0.f, 0.f, 0.f, 0.f}, f32x4{0.f, 0.f, 0.f, 0.f}};
#pragma unroll
                for (int kt = 0; kt < 4; ++kt)
#pragma unroll
                    for (int ntl = 0; ntl < 2; ++ntl)
                        acc2[ntl] = __builtin_amdgcn_mfma_f32_16x16x32_bf16(hf[kt], w2r[ntl][kt], acc2[ntl], 0, 0, 0);
                // BN+relu -> bf16 into Alds rows of this half (agg already consumed)
#pragma unroll
                for (int ntl = 0; ntl < 2; ++ntl) {
                    int colb = (2 * w + ntl) * 16 + lrow;
#pragma unroll
                    for (int r = 0; r < 4; ++r) {
                        int row = hh * 32 + mt * 16 + lchk * 4 + r;
                        float o = fmaxf(acc2[ntl][r] * sc[ntl] + of[ntl], 0.f);
                        int byte = (row * 256 + colb * 2) ^ ((row & 7) << 4);
                        *(ushort*)((char*)Alds + byte) = f2bf(o);
                    }
                }
            }
        } else {
            // DOUT=64: waves 0,1 handle the half's two 16-row tiles (row-local softmax)
            if (w < 2) {
                const bf16x8* __restrict__ w2p = (const bf16x8*)W2f;
                bf16x8 hf[4];
#pragma unroll
                for (int kt = 0; kt < 4; ++kt) {
                    int rloc = w * 16 + lrow;
                    int byte = (rloc * 256 + kt * 64 + lchk * 16) ^ ((rloc & 7) << 4);
                    hf[kt] = *(const bf16x8*)((char*)Hlds + byte);
                }
                f32x4 acc2[4];
#pragma unroll
                for (int nt = 0; nt < 4; ++nt) acc2[nt] = f32x4{0.f, 0.f, 0.f, 0.f};
#pragma unroll
                for (int kt = 0; kt < 4; ++kt)
#pragma unroll
                    for (int nt = 0; nt < 4; ++nt)
                        acc2[nt] = __builtin_amdgcn_mfma_f32_16x16x32_bf16(hf[kt], w2p[(kt * 4 + nt) * 64 + l], acc2[nt], 0, 0, 0);
                float bb[4];
#pragma unroll
                for (int nt = 0; nt < 4; ++nt) bb[nt] = b2[nt * 16 + lrow];
#pragma unroll
                for (int r = 0; r < 4; ++r) {
                    float v0 = acc2[0][r] + bb[0], v1 = acc2[1][r] + bb[1];
                    float v2 = acc2[2][r] + bb[2], v3 = acc2[3][r] + bb[3];
                    float mx = fmaxf(fmaxf(v0, v1), fmaxf(v2, v3));
                    for (int d = 1; d < 16; d <<= 1) mx = fmaxf(mx, __shfl_xor(mx, d));
                    float sm = expf(v0 - mx) + expf(v1 - mx) + expf(v2 - mx) + expf(v3 - mx);
                    for (int d = 1; d < 16; d <<= 1) sm += __shfl_xor(sm, d);
                    float L = mx + logf(sm);
                    int grow = R0 + hh * 32 + w * 16 + lchk * 4 + r;
                    if (grow < NN) {
                        outf[(size_t)grow * 64 + 0 + lrow] = v0 - L;
                        outf[(size_t)grow * 64 + 16 + lrow] = v1 - L;
                        outf[(size_t)grow * 64 + 32 + lrow] = v2 - L;
                        outf[(size_t)grow * 64 + 48 + lrow] = v3 - L;
                    }
                }
            }
        }
        __syncthreads();
    }

    // ---- epilogue repack: coalesced residual add + dual store (bf16 + fp8) ----
    if constexpr (FINAL == 0) {
        us8* __restrict__ ob8 = (us8*)outb;
        ui2* __restrict__ oq2 = (ui2*)outq;
#pragma unroll
        for (int j = 0; j < 4; ++j) {
            int i = t + 256 * j;
            int row = i >> 4, chunk = i & 15;
            int grow = R0 + row;
            if (grow < NN) {
                int byte = (row * 256 + chunk * 16) ^ ((row & 7) << 4);
                us8 h8 = *(const us8*)((char*)Alds + byte);
                us8 r8 = xv[(size_t)grow * 16 + chunk];
                float oo[8];
#pragma unroll
                for (int e = 0; e < 8; ++e) oo[e] = bf2f(h8[e]) + bf2f(r8[e]);
                us8 o8;
#pragma unroll
                for (int e = 0; e < 8; ++e) o8[e] = f2bf(oo[e]);
                ob8[(size_t)grow * 16 + chunk] = o8;
                oq2[(size_t)grow * 16 + chunk] = f32_fp8x8(oo);
            }
        }
    }
}

extern "C" void kernel_launch(void* const* d_in, const int* in_sizes, int n_in,
                              void* d_out, int out_size, void* d_ws, size_t ws_size,
                              hipStream_t stream) {
    const float* x = (const float*)d_in[0];
    const int* ei = (const int*)d_in[1];
    const float* W1_0 = (const float*)d_in[2];
    const float* b1_0 = (const float*)d_in[3];
    const float* W2_0 = (const float*)d_in[4];
    const float* b2_0 = (const float*)d_in[5];
    const float* W1_1 = (const float*)d_in[6];
    const float* b1_1 = (const float*)d_in[7];
    const float* W2_1 = (const float*)d_in[8];
    const float* b2_1 = (const float*)d_in[9];
    const float* W1_2 = (const float*)d_in[10];
    const float* b1_2 = (const float*)d_in[11];
    const float* W2_2 = (const float*)d_in[12];
    const float* b2_2 = (const float*)d_in[13];
    const float* g0 = (const float*)d_in[14];
    const float* be0 = (const float*)d_in[15];
    const float* m0 = (const float*)d_in[16];
    const float* v0 = (const float*)d_in[17];
    const float* g1 = (const float*)d_in[18];
    const float* be1 = (const float*)d_in[19];
    const float* m1 = (const float*)d_in[20];
    const float* v1 = (const float*)d_in[21];
    float* out = (float*)d_out;

    // ws layout (bytes): xb0 25.6M | xb1 25.6M | xq0 12.8M | xq1 12.8M |
    // packed/col 12.8M | rpS 400K | rpE 400K | bcur 4K | perm 401K | Wf
    char* ws = (char*)d_ws;
    ushort* xb0 = (ushort*)(ws);
    ushort* xb1 = (ushort*)(ws + 25600000);
    unsigned* xq0 = (unsigned*)(ws + 51200000);
    unsigned* xq1 = (unsigned*)(ws + 64000000);
    unsigned* packed = (unsigned*)(ws + 76800000);     // also final col
    int* rpS = (int*)(ws + 76800000 + 12812288);
    int* rpE = (int*)(ws + 76800000 + 12812288 + 400128);
    int* bcur = (int*)(ws + 76800000 + 12812288 + 800256);
    int* perm = (int*)(ws + 76800000 + 12812288 + 800256 + 4096);   // NB*2*64 ints
    ushort* W10f = (ushort*)(ws + 76800000 + 12812288 + 800256 + 4096 + 401408);
    ushort* W20f = W10f + 16384;
    ushort* W11f = W20f + 16384;
    ushort* W21f = W11f + 16384;
    ushort* W12f = W21f + 16384;
    ushort* W22f = W12f + 16384;

    // --- prep (overlapped): zero cursors; scatter || convert || pack; then CSR sort ---
    hipMemsetAsync(bcur, 0, NB * sizeof(int), stream);
    prep1_k<<<NEB + CVB + 48, 256, 0, stream>>>(ei, bcur, packed, x, xb0, xq0,
                                                W1_0, W2_0, W1_1, W2_1, W1_2, W2_2,
                                                W10f, W20f, W11f, W21f, W12f, W22f);
    prep2_k<<<NB, 256, 0, stream>>>(packed, bcur, rpS, rpE, perm);

    const int GG = (NN + 63) / 64;  // 1563

    // one fused kernel per layer: fp8 gather-agg + MLP + epilogue
    fused_k<0><<<GG, 256, 0, stream>>>(xb0, xq0, rpS, rpE, packed, perm, W10f, W20f, b1_0, b2_0,
                                       g0, be0, m0, v0, xb1, xq1, nullptr);
    fused_k<0><<<GG, 256, 0, stream>>>(xb1, xq1, rpS, rpE, packed, perm, W11f, W21f, b1_1, b2_1,
                                       g1, be1, m1, v1, xb0, xq0, nullptr);
    fused_k<1><<<GG, 256, 0, stream>>>(xb0, xq0, rpS, rpE, packed, perm, W12f, W22f, b1_2, b2_2,
                                       nullptr, nullptr, nullptr, nullptr, nullptr, nullptr, out);
}

// Round 18
// 226.998 us; speedup vs baseline: 1.6090x; 1.0914x over previous
//
#include <hip/hip_runtime.h>
#include <math.h>

#define NN 100000
#define NE 1600000
#define BN_EPS 1e-5f
#define NB 782            // buckets of 128 nodes
#define BCAP 4096         // fixed bucket capacity (avg 2046, sigma 45)
#define EPB 4096
#define NEB ((NE + EPB - 1) / EPB)   // 391
#define CVB 12500         // cvtx blocks

typedef short bf16x8 __attribute__((ext_vector_type(8)));
typedef float f32x4 __attribute__((ext_vector_type(4)));
typedef float f32x2 __attribute__((ext_vector_type(2)));
typedef unsigned short ushort;
typedef ushort us8 __attribute__((ext_vector_type(8)));
typedef ushort us4 __attribute__((ext_vector_type(4)));
typedef unsigned ui2 __attribute__((ext_vector_type(2)));

__device__ __forceinline__ ushort f2bf(float f) {
    unsigned u = __float_as_uint(f);
    unsigned r = (u + 0x7FFFu + ((u >> 16) & 1u)) >> 16;
    return (ushort)r;
}
__device__ __forceinline__ float bf2f(ushort h) { return __uint_as_float(((unsigned)h) << 16); }

// 8 fp8(e4m3) bytes -> 8 floats via HW cvt (gfx950 OCP format)
__device__ __forceinline__ void fp8x8_f32(ui2 q, float* f) {
    f32x2 p;
    p = __builtin_amdgcn_cvt_pk_f32_fp8((int)q[0], false); f[0] = p[0]; f[1] = p[1];
    p = __builtin_amdgcn_cvt_pk_f32_fp8((int)q[0], true);  f[2] = p[0]; f[3] = p[1];
    p = __builtin_amdgcn_cvt_pk_f32_fp8((int)q[1], false); f[4] = p[0]; f[5] = p[1];
    p = __builtin_amdgcn_cvt_pk_f32_fp8((int)q[1], true);  f[6] = p[0]; f[7] = p[1];
}
// 8 floats -> 8 fp8 bytes
__device__ __forceinline__ ui2 f32_fp8x8(const float* f) {
    int d0 = __builtin_amdgcn_cvt_pk_fp8_f32(f[0], f[1], 0, false);
    d0 = __builtin_amdgcn_cvt_pk_fp8_f32(f[2], f[3], d0, true);
    int d1 = __builtin_amdgcn_cvt_pk_fp8_f32(f[4], f[5], 0, false);
    d1 = __builtin_amdgcn_cvt_pk_fp8_f32(f[6], f[7], d1, true);
    ui2 r; r[0] = (unsigned)d0; r[1] = (unsigned)d1; return r;
}

// ---------------- prep1: edge scatter (blocks [0,NEB)) || x convert (rest) ----------------
// bcur must be zeroed beforehand (hipMemsetAsync); bucket base folded in at reservation.
__global__ __launch_bounds__(256) void prep1_k(const int* __restrict__ ei, int* __restrict__ bcur,
                                               unsigned* __restrict__ packed,
                                               const float* __restrict__ x, ushort* __restrict__ xb,
                                               unsigned* __restrict__ xq) {
    __shared__ int h[NB];
    if (blockIdx.x >= NEB) {
        // ---- cvtx part: fp32 -> bf16 + fp8 ----
        int i = (blockIdx.x - NEB) * 256 + threadIdx.x;
        float4 v = ((const float4*)x)[i];
        us4 o;
        o[0] = f2bf(v.x); o[1] = f2bf(v.y); o[2] = f2bf(v.z); o[3] = f2bf(v.w);
        ((us4*)xb)[i] = o;
        int d = __builtin_amdgcn_cvt_pk_fp8_f32(v.x, v.y, 0, false);
        d = __builtin_amdgcn_cvt_pk_fp8_f32(v.z, v.w, d, true);
        xq[i] = (unsigned)d;
        return;
    }
    // ---- bscat part ----
    for (int i = threadIdx.x; i < NB; i += 256) h[i] = 0;
    __syncthreads();
    int base = blockIdx.x * EPB;
    for (int i = threadIdx.x; i < EPB; i += 256) {
        int e = base + i;
        if (e < NE) atomicAdd(&h[ei[NE + e] >> 7], 1);
    }
    __syncthreads();
    for (int i = threadIdx.x; i < NB; i += 256) {
        int c = h[i];
        if (c) h[i] = (i << 12) + atomicAdd(&bcur[i], c);   // global cursor for this block's run
    }
    __syncthreads();
    for (int i = threadIdx.x; i < EPB; i += 256) {
        int e = base + i;
        if (e < NE) {
            int d = ei[NE + e];
            int b = d >> 7;
            int pos = atomicAdd(&h[b], 1);
            packed[pos] = (unsigned)ei[e] | ((unsigned)(d & 127) << 17);
        }
    }
}

// ---------------- prep2: per-bucket CSR sort + perm (blocks [0,NB)) || weight pack (rest) ----------------
__global__ __launch_bounds__(256) void prep2_k(
    unsigned* __restrict__ packed, const int* __restrict__ bcur,
    int* __restrict__ rpS, int* __restrict__ rpE, int* __restrict__ perm,
    const float* __restrict__ Wa, const float* __restrict__ Wb, const float* __restrict__ Wc,
    const float* __restrict__ Wd, const float* __restrict__ We, const float* __restrict__ Wf_,
    ushort* __restrict__ Fa, ushort* __restrict__ Fb, ushort* __restrict__ Fc,
    ushort* __restrict__ Fd, ushort* __restrict__ Fe, ushort* __restrict__ Ff) {
    __shared__ unsigned ent[BCAP];     // 16 KB
    __shared__ int hc[128], hb[128], sc[128];
    if (blockIdx.x >= NB) {
        // ---- packall part ----
        int bb = blockIdx.x - NB;
        int which = bb >> 3, sub = bb & 7;
        const float* W; ushort* F; int DOUT = 128;
        switch (which) {
            case 0: W = Wa; F = Fa; break;
            case 1: W = Wb; F = Fb; break;
            case 2: W = Wc; F = Fc; break;
            case 3: W = Wd; F = Fd; break;
            case 4: W = We; F = Fe; break;
            default: W = Wf_; F = Ff; DOUT = 64; break;
        }
        int NT = DOUT / 16;
        int idx = sub * 256 + threadIdx.x;
        if (idx >= 4 * NT * 64) return;
        int l = idx & 63;
        int nt = (idx >> 6) % NT;
        int kt = idx / (NT * 64);
        int colw = nt * 16 + (l & 15);
        int k0 = kt * 32 + (l >> 4) * 8;
        us8 o;
#pragma unroll
        for (int e = 0; e < 8; ++e) o[e] = f2bf(W[(k0 + e) * DOUT + colw]);
        ((us8*)F)[idx] = o;
        return;
    }
    // ---- csr part ----
    int t = threadIdx.x, b = blockIdx.x;
    int base = b << 12;
    int nb = bcur[b];                  // bcur holds per-bucket count (0-based cursors)
    if (nb > BCAP) nb = BCAP;
    for (int i = t; i < nb; i += 256) ent[i] = packed[base + i];
    if (t < 128) hc[t] = 0;
    __syncthreads();
    for (int i = t; i < nb; i += 256) atomicAdd(&hc[ent[i] >> 17], 1);
    __syncthreads();
    if (t < 128) sc[t] = hc[t];
    __syncthreads();
    for (int off = 1; off < 128; off <<= 1) {
        int u = 0;
        if (t < 128 && t >= off) u = sc[t - off];
        __syncthreads();
        if (t < 128) sc[t] += u;
        __syncthreads();
    }
    if (t < 128) {
        int ex = sc[t] - hc[t];
        hb[t] = ex;
        int node = b * 128 + t;
        if (node < NN) {
            rpS[node] = base + ex;
            rpE[node] = base + sc[t];
        }
    }
    __syncthreads();
    for (int i = t; i < nb; i += 256) {
        unsigned u = ent[i];
        int pos = atomicAdd(&hb[u >> 17], 1);
        packed[base + pos] = u & 0x1FFFFu;
    }
    // degree-rank each 64-node tile -> perm (waves then co-process equal-degree nodes)
    if (t < 128) {
        int half = t >> 6, li = t & 63;
        int mydeg = (b * 128 + t < NN) ? hc[t] : -1;
        int rank = 0;
#pragma unroll 8
        for (int j = 0; j < 64; ++j) {
            int oj = half * 64 + j;
            int od = (b * 128 + oj < NN) ? hc[oj] : -1;
            rank += (od > mydeg) || (od == mydeg && j < li);
        }
        perm[(b * 2 + half) * 64 + rank] = li;
    }
}

// ---------------- fused layer: fp8 gather-agg (degree-sorted) -> Alds -> MLP -> epilogue ----------------
// 256 threads = 4 waves, 64 rows/block. Neighbor gather reads the fp8 copy XQ
// (128B/row); self + residual use the exact bf16 copy X. Node order within the
// block follows the degree-sorted perm so a wave's 4 concurrent nodes have
// near-equal degree (minimal idle-lane trips).
// FINAL=0: BN+relu+residual -> bf16 outb + fp8 outq.  FINAL=1: log_softmax -> fp32 outf.
template <int FINAL>
__global__ __launch_bounds__(256, 4) void fused_k(
    const ushort* __restrict__ X, const unsigned* __restrict__ XQ,
    const int* __restrict__ rpS, const int* __restrict__ rpE,
    const unsigned* __restrict__ col, const int* __restrict__ perm,
    const ushort* __restrict__ W1f, const ushort* __restrict__ W2f,
    const float* __restrict__ b1, const float* __restrict__ b2,
    const float* __restrict__ bng, const float* __restrict__ bnb,
    const float* __restrict__ bnm, const float* __restrict__ bnv,
    ushort* __restrict__ outb, unsigned* __restrict__ outq, float* __restrict__ outf) {
    __shared__ ushort Alds[8192];   // 16KB: 64 x 128 bf16, XOR-swizzled (agg tile)
    __shared__ ushort Hlds[8192];
    __shared__ int pLds[64];
    const int t = threadIdx.x;
    const int w = t >> 6, l = t & 63;
    const int lrow = l & 15, lchk = l >> 4;
    const int R0 = blockIdx.x * 64;
    const us8* __restrict__ xv = (const us8*)X;
    const ui2* __restrict__ xq2 = (const ui2*)XQ;   // row = 16 x ui2 (8 fp8 each)

    if (t < 64) pLds[t] = perm[blockIdx.x * 64 + t];
    __syncthreads();

    // ---- gather-aggregate: 4 iterations x 16 nodes, 16 lanes (8 features) per node ----
    const int ch = t & 15;
#pragma unroll
    for (int it = 0; it < 4; ++it) {
        int nl = pLds[it * 16 + (t >> 4)];
        int node = R0 + nl;
        float a[8];
#pragma unroll
        for (int i = 0; i < 8; ++i) a[i] = 0.f;
        if (node < NN) {
            us8 self = xv[(size_t)node * 16 + ch];
#pragma unroll
            for (int i = 0; i < 8; ++i) a[i] = bf2f(self[i]);
            int p = rpS[node];
            const int pe = rpE[node];
            for (; p + 7 < pe; p += 8) {
                unsigned s[8];
#pragma unroll
                for (int u = 0; u < 8; ++u) s[u] = col[p + u];
                ui2 v[8];
#pragma unroll
                for (int u = 0; u < 8; ++u) v[u] = xq2[(size_t)s[u] * 16 + ch];
#pragma unroll
                for (int u = 0; u < 8; ++u) {
                    float f[8];
                    fp8x8_f32(v[u], f);
#pragma unroll
                    for (int i = 0; i < 8; ++i) a[i] += f[i];
                }
            }
            for (; p + 3 < pe; p += 4) {
                ui2 v0 = xq2[(size_t)col[p] * 16 + ch];
                ui2 v1 = xq2[(size_t)col[p + 1] * 16 + ch];
                ui2 v2 = xq2[(size_t)col[p + 2] * 16 + ch];
                ui2 v3 = xq2[(size_t)col[p + 3] * 16 + ch];
                float f0[8], f1[8], f2[8], f3[8];
                fp8x8_f32(v0, f0); fp8x8_f32(v1, f1); fp8x8_f32(v2, f2); fp8x8_f32(v3, f3);
#pragma unroll
                for (int i = 0; i < 8; ++i) a[i] += (f0[i] + f1[i]) + (f2[i] + f3[i]);
            }
            for (; p < pe; ++p) {
                ui2 v = xq2[(size_t)col[p] * 16 + ch];
                float f[8];
                fp8x8_f32(v, f);
#pragma unroll
                for (int i = 0; i < 8; ++i) a[i] += f[i];
            }
        }
        us8 o;
#pragma unroll
        for (int i = 0; i < 8; ++i) o[i] = f2bf(a[i]);
        int byte = (nl * 256 + ch * 16) ^ ((nl & 7) << 4);
        *(us8*)((char*)Alds + byte) = o;
    }

    // W1 frags for this wave's 2 hidden-col tiles
    const bf16x8* __restrict__ w1p = (const bf16x8*)W1f;
    bf16x8 w1r[2][4];
#pragma unroll
    for (int ntl = 0; ntl < 2; ++ntl)
#pragma unroll
        for (int kt = 0; kt < 4; ++kt)
            w1r[ntl][kt] = w1p[(kt * 8 + (2 * w + ntl)) * 64 + l];

    __syncthreads();

    // ---- stage 1: h = relu(agg @ W1 + b1) ----
#pragma unroll
    for (int mt = 0; mt < 4; ++mt) {
        bf16x8 af[4];
#pragma unroll
        for (int kt = 0; kt < 4; ++kt) {
            int row = mt * 16 + lrow;
            int byte = (row * 256 + kt * 64 + lchk * 16) ^ ((row & 7) << 4);
            af[kt] = *(const bf16x8*)((char*)Alds + byte);
        }
        f32x4 acc[2] = {f32x4{0.f, 0.f, 0.f, 0.f}, f32x4{0.f, 0.f, 0.f, 0.f}};
#pragma unroll
        for (int kt = 0; kt < 4; ++kt)
#pragma unroll
            for (int ntl = 0; ntl < 2; ++ntl)
                acc[ntl] = __builtin_amdgcn_mfma_f32_16x16x32_bf16(af[kt], w1r[ntl][kt], acc[ntl], 0, 0, 0);
#pragma unroll
        for (int ntl = 0; ntl < 2; ++ntl) {
            int colb = (2 * w + ntl) * 16 + lrow;
            float bias = b1[colb];
#pragma unroll
            for (int r = 0; r < 4; ++r) {
                int rloc = mt * 16 + lchk * 4 + r;
                float hv = fmaxf(acc[ntl][r] + bias, 0.f);
                int byte = (rloc * 256 + colb * 2) ^ ((rloc & 7) << 4);
                *(ushort*)((char*)Hlds + byte) = f2bf(hv);
            }
        }
    }
    __syncthreads();

    // ---- stage 2 ----
    if constexpr (FINAL == 0) {
        const bf16x8* __restrict__ w2p = (const bf16x8*)W2f;
        bf16x8 w2r[2][4];
#pragma unroll
        for (int ntl = 0; ntl < 2; ++ntl)
#pragma unroll
            for (int kt = 0; kt < 4; ++kt)
                w2r[ntl][kt] = w2p[(kt * 8 + (2 * w + ntl)) * 64 + l];
        float sc[2], of[2];
#pragma unroll
        for (int ntl = 0; ntl < 2; ++ntl) {
            int colb = (2 * w + ntl) * 16 + lrow;
            sc[ntl] = bng[colb] * rsqrtf(bnv[colb] + BN_EPS);
            of[ntl] = (b2[colb] - bnm[colb]) * sc[ntl] + bnb[colb];
        }
#pragma unroll
        for (int mt = 0; mt < 4; ++mt) {
            bf16x8 hf[4];
#pragma unroll
            for (int kt = 0; kt < 4; ++kt) {
                int row = mt * 16 + lrow;
                int byte = (row * 256 + kt * 64 + lchk * 16) ^ ((row & 7) << 4);
                hf[kt] = *(const bf16x8*)((char*)Hlds + byte);
            }
            f32x4 acc2[2] = {f32x4{0.f, 0.f, 0.f, 0.f}, f32x4{0.f, 0.f, 0.f, 0.f}};
#pragma unroll
            for (int kt = 0; kt < 4; ++kt)
#pragma unroll
                for (int ntl = 0; ntl < 2; ++ntl)
                    acc2[ntl] = __builtin_amdgcn_mfma_f32_16x16x32_bf16(hf[kt], w2r[ntl][kt], acc2[ntl], 0, 0, 0);
            // BN+relu -> bf16 into Alds (dead after stage 1; barrier above ordered reads)
#pragma unroll
            for (int ntl = 0; ntl < 2; ++ntl) {
                int colb = (2 * w + ntl) * 16 + lrow;
#pragma unroll
                for (int r = 0; r < 4; ++r) {
                    int rloc = mt * 16 + lchk * 4 + r;
                    float o = fmaxf(acc2[ntl][r] * sc[ntl] + of[ntl], 0.f);
                    int byte = (rloc * 256 + colb * 2) ^ ((rloc & 7) << 4);
                    *(ushort*)((char*)Alds + byte) = f2bf(o);
                }
            }
        }
        __syncthreads();
        // repack -> coalesced residual add + dual store (bf16 + fp8)
        us8* __restrict__ ob8 = (us8*)outb;
        ui2* __restrict__ oq2 = (ui2*)outq;
#pragma unroll
        for (int j = 0; j < 4; ++j) {
            int i = t + 256 * j;
            int row = i >> 4, chunk = i & 15;
            int grow = R0 + row;
            if (grow < NN) {
                int byte = (row * 256 + chunk * 16) ^ ((row & 7) << 4);
                us8 h8 = *(const us8*)((char*)Alds + byte);
                us8 r8 = xv[(size_t)grow * 16 + chunk];
                float oo[8];
#pragma unroll
                for (int e = 0; e < 8; ++e) oo[e] = bf2f(h8[e]) + bf2f(r8[e]);
                us8 o8;
#pragma unroll
                for (int e = 0; e < 8; ++e) o8[e] = f2bf(oo[e]);
                ob8[(size_t)grow * 16 + chunk] = o8;
                oq2[(size_t)grow * 16 + chunk] = f32_fp8x8(oo);
            }
        }
    } else {
        // DOUT=64: wave w handles row-tile mt=w with all 4 col tiles (row-local softmax)
        const bf16x8* __restrict__ w2p = (const bf16x8*)W2f;
        bf16x8 hf[4];
#pragma unroll
        for (int kt = 0; kt < 4; ++kt) {
            int row = w * 16 + lrow;
            int byte = (row * 256 + kt * 64 + lchk * 16) ^ ((row & 7) << 4);
            hf[kt] = *(const bf16x8*)((char*)Hlds + byte);
        }
        f32x4 acc2[4];
#pragma unroll
        for (int nt = 0; nt < 4; ++nt) acc2[nt] = f32x4{0.f, 0.f, 0.f, 0.f};
#pragma unroll
        for (int kt = 0; kt < 4; ++kt)
#pragma unroll
            for (int nt = 0; nt < 4; ++nt)
                acc2[nt] = __builtin_amdgcn_mfma_f32_16x16x32_bf16(hf[kt], w2p[(kt * 4 + nt) * 64 + l], acc2[nt], 0, 0, 0);
        float bb[4];
#pragma unroll
        for (int nt = 0; nt < 4; ++nt) bb[nt] = b2[nt * 16 + lrow];
#pragma unroll
        for (int r = 0; r < 4; ++r) {
            float v0 = acc2[0][r] + bb[0], v1 = acc2[1][r] + bb[1];
            float v2 = acc2[2][r] + bb[2], v3 = acc2[3][r] + bb[3];
            float mx = fmaxf(fmaxf(v0, v1), fmaxf(v2, v3));
            for (int d = 1; d < 16; d <<= 1) mx = fmaxf(mx, __shfl_xor(mx, d));
            float sm = expf(v0 - mx) + expf(v1 - mx) + expf(v2 - mx) + expf(v3 - mx);
            for (int d = 1; d < 16; d <<= 1) sm += __shfl_xor(sm, d);
            float L = mx + logf(sm);
            int grow = R0 + w * 16 + lchk * 4 + r;
            if (grow < NN) {
                outf[(size_t)grow * 64 + 0 + lrow] = v0 - L;
                outf[(size_t)grow * 64 + 16 + lrow] = v1 - L;
                outf[(size_t)grow * 64 + 32 + lrow] = v2 - L;
                outf[(size_t)grow * 64 + 48 + lrow] = v3 - L;
            }
        }
    }
}

extern "C" void kernel_launch(void* const* d_in, const int* in_sizes, int n_in,
                              void* d_out, int out_size, void* d_ws, size_t ws_size,
                              hipStream_t stream) {
    const float* x = (const float*)d_in[0];
    const int* ei = (const int*)d_in[1];
    const float* W1_0 = (const float*)d_in[2];
    const float* b1_0 = (const float*)d_in[3];
    const float* W2_0 = (const float*)d_in[4];
    const float* b2_0 = (const float*)d_in[5];
    const float* W1_1 = (const float*)d_in[6];
    const float* b1_1 = (const float*)d_in[7];
    const float* W2_1 = (const float*)d_in[8];
    const float* b2_1 = (const float*)d_in[9];
    const float* W1_2 = (const float*)d_in[10];
    const float* b1_2 = (const float*)d_in[11];
    const float* W2_2 = (const float*)d_in[12];
    const float* b2_2 = (const float*)d_in[13];
    const float* g0 = (const float*)d_in[14];
    const float* be0 = (const float*)d_in[15];
    const float* m0 = (const float*)d_in[16];
    const float* v0 = (const float*)d_in[17];
    const float* g1 = (const float*)d_in[18];
    const float* be1 = (const float*)d_in[19];
    const float* m1 = (const float*)d_in[20];
    const float* v1 = (const float*)d_in[21];
    float* out = (float*)d_out;

    // ws layout (bytes): xb0 25.6M | xb1 25.6M | xq0 12.8M | xq1 12.8M |
    // packed/col 12.8M | rpS 400K | rpE 400K | bcur 4K | perm 401K | Wf
    char* ws = (char*)d_ws;
    ushort* xb0 = (ushort*)(ws);
    ushort* xb1 = (ushort*)(ws + 25600000);
    unsigned* xq0 = (unsigned*)(ws + 51200000);
    unsigned* xq1 = (unsigned*)(ws + 64000000);
    unsigned* packed = (unsigned*)(ws + 76800000);     // also final col
    int* rpS = (int*)(ws + 76800000 + 12812288);
    int* rpE = (int*)(ws + 76800000 + 12812288 + 400128);
    int* bcur = (int*)(ws + 76800000 + 12812288 + 800256);
    int* perm = (int*)(ws + 76800000 + 12812288 + 800256 + 4096);   // NB*2*64 ints
    ushort* W10f = (ushort*)(ws + 76800000 + 12812288 + 800256 + 4096 + 401408);
    ushort* W20f = W10f + 16384;
    ushort* W11f = W20f + 16384;
    ushort* W21f = W11f + 16384;
    ushort* W12f = W21f + 16384;
    ushort* W22f = W12f + 16384;

    // --- prep (overlapped): zero cursors; scatter || convert; sort || pack ---
    hipMemsetAsync(bcur, 0, NB * sizeof(int), stream);
    prep1_k<<<NEB + CVB, 256, 0, stream>>>(ei, bcur, packed, x, xb0, xq0);
    prep2_k<<<NB + 48, 256, 0, stream>>>(packed, bcur, rpS, rpE, perm,
                                         W1_0, W2_0, W1_1, W2_1, W1_2, W2_2,
                                         W10f, W20f, W11f, W21f, W12f, W22f);

    const int GG = (NN + 63) / 64;  // 1563

    // one fused kernel per layer: fp8 gather-agg + MLP + epilogue
    fused_k<0><<<GG, 256, 0, stream>>>(xb0, xq0, rpS, rpE, packed, perm, W10f, W20f, b1_0, b2_0,
                                       g0, be0, m0, v0, xb1, xq1, nullptr);
    fused_k<0><<<GG, 256, 0, stream>>>(xb1, xq1, rpS, rpE, packed, perm, W11f, W21f, b1_1, b2_1,
                                       g1, be1, m1, v1, xb0, xq0, nullptr);
    fused_k<1><<<GG, 256, 0, stream>>>(xb0, xq0, rpS, rpE, packed, perm, W12f, W22f, b1_2, b2_2,
                                       nullptr, nullptr, nullptr, nullptr, nullptr, nullptr, out);
}